// Round 1
// baseline (6226.578 us; speedup 1.0000x reference)
//
#include <hip/hip_runtime.h>
#include <stdint.h>

#define B_   256
#define T_   1024
#define H_   512
#define NIN_ 64
#define NOUT_ 64

#define NW    8      // waves per workgroup (recurrent kernel)
#define BBLK  4      // batch rows per workgroup
#define LDSPAD 528   // 512 + 16 shorts: row stride 1056B -> 8-bank shift/row -> <=2-way conflicts

typedef __attribute__((ext_vector_type(8))) short bf16x8;
typedef __attribute__((ext_vector_type(4))) float f32x4;

__device__ __forceinline__ short f2bf(float f) {
  // round-to-nearest-even f32 -> bf16 bit pattern
  uint32_t u = __float_as_uint(f);
  uint32_t r = (u + 0x7FFFu + ((u >> 16) & 1u)) >> 16;
  return (short)(r & 0xFFFFu);
}

__device__ __forceinline__ bf16x8 pack8(float4 lo, float4 hi) {
  bf16x8 s;
  s[0] = f2bf(lo.x); s[1] = f2bf(lo.y); s[2] = f2bf(lo.z); s[3] = f2bf(lo.w);
  s[4] = f2bf(hi.x); s[5] = f2bf(hi.y); s[6] = f2bf(hi.z); s[7] = f2bf(hi.w);
  return s;
}

__device__ __forceinline__ float fast_tanh(float x) {
  // tanh(x) = 1 - 2/(exp(2x)+1); robust at +-inf
  float e = __expf(2.0f * x);
  return 1.0f - __fdividef(2.0f, e + 1.0f);
}

// ---------------------------------------------------------------------------
// Persistent RNN scan. Each WG owns BBLK batch rows for all T steps.
// Wave w holds W columns [64w, 64w+64) as bf16 MFMA B-fragments in registers.
// tanh(h) is exchanged through a double-buffered LDS tile each step.
// MFMA layout (16x16x32 bf16):
//   A: lane l, reg e -> A[l&15][(l>>4)*8 + e]
//   B: lane l, reg e -> B[(l>>4)*8 + e][l&15]
//   D: lane l, reg r -> D[(l>>4)*4 + r][l&15]   (m89-verified)
// BBLK=4 rows are replicated 4x across the 16 M-rows (broadcast LDS reads).
// ---------------------------------------------------------------------------
__global__ __launch_bounds__(NW * 64) void rnn_scan(
    const float* __restrict__ X, const float* __restrict__ h0,
    const float* __restrict__ W, const float* __restrict__ Win,
    float* __restrict__ hid)
{
  __shared__ __align__(16) short hbuf[2][BBLK][LDSPAD];

  const int tid  = threadIdx.x;
  const int lane = tid & 63;
  const int w    = tid >> 6;    // wave 0..7
  const int g    = lane >> 4;   // k-group 0..3
  const int m    = lane & 15;   // M/N lane index
  const int b0   = blockIdx.x * BBLK;

  // --- persistent W fragments: B[k][n] = W[n][k], wave cols j = 64w+16jt+m
  bf16x8 Wf[16][4];
#pragma unroll
  for (int kb = 0; kb < 16; ++kb) {
#pragma unroll
    for (int jt = 0; jt < 4; ++jt) {
      const int j = 64 * w + 16 * jt + m;
      const float4* p = reinterpret_cast<const float4*>(W + j * H_ + 32 * kb + 8 * g);
      Wf[kb][jt] = pack8(p[0], p[1]);
    }
  }
  // --- persistent W_in fragments (K=64)
  bf16x8 WIf[2][4];
#pragma unroll
  for (int kb = 0; kb < 2; ++kb) {
#pragma unroll
    for (int jt = 0; jt < 4; ++jt) {
      const int j = 64 * w + 16 * jt + m;
      const float4* p = reinterpret_cast<const float4*>(Win + j * NIN_ + 32 * kb + 8 * g);
      WIf[kb][jt] = pack8(p[0], p[1]);
    }
  }

  // --- stage tanh(h0) into LDS buffer 0
  for (int e = tid; e < BBLK * H_; e += NW * 64) {
    const int r = e >> 9;          // H_=512
    const int k = e & (H_ - 1);
    hbuf[0][r][k] = f2bf(fast_tanh(h0[(b0 + r) * H_ + k]));
  }

  // --- X prefetch for t=0 (A-frag of input projection; rows replicated)
  const int brow = b0 + (m & 3);
  float4 xlo0, xhi0, xlo1, xhi1;
  {
    const float4* p0 = reinterpret_cast<const float4*>(X + (brow * T_ + 0) * NIN_ + 8 * g);
    xlo0 = p0[0]; xhi0 = p0[1];
    const float4* p1 = reinterpret_cast<const float4*>(X + (brow * T_ + 0) * NIN_ + 32 + 8 * g);
    xlo1 = p1[0]; xhi1 = p1[1];
  }

  __syncthreads();

  const f32x4 zero = {0.f, 0.f, 0.f, 0.f};

  for (int t = 0; t < T_; ++t) {
    const int cur = t & 1, nxt = cur ^ 1;

    // input projection: acc = X_t @ Win^T  (2 K-frags)
    const bf16x8 ax0 = pack8(xlo0, xhi0);
    const bf16x8 ax1 = pack8(xlo1, xhi1);
    f32x4 acc[4];
#pragma unroll
    for (int jt = 0; jt < 4; ++jt) {
      acc[jt] = __builtin_amdgcn_mfma_f32_16x16x32_bf16(ax0, WIf[0][jt], zero, 0, 0, 0);
      acc[jt] = __builtin_amdgcn_mfma_f32_16x16x32_bf16(ax1, WIf[1][jt], acc[jt], 0, 0, 0);
    }

    // prefetch X for t+1 (uniform; last iteration re-reads t harmlessly)
    {
      const int tn = (t + 1 < T_) ? (t + 1) : t;
      const float4* p0 = reinterpret_cast<const float4*>(X + (brow * T_ + tn) * NIN_ + 8 * g);
      xlo0 = p0[0]; xhi0 = p0[1];
      const float4* p1 = reinterpret_cast<const float4*>(X + (brow * T_ + tn) * NIN_ + 32 + 8 * g);
      xlo1 = p1[0]; xhi1 = p1[1];
    }

    // recurrence: acc += tanh(h) @ W^T ; A rows replicated (m&3)
    const int arow = m & 3;
#pragma unroll
    for (int kb = 0; kb < 16; ++kb) {
      const bf16x8 a = *reinterpret_cast<const bf16x8*>(&hbuf[cur][arow][32 * kb + 8 * g]);
#pragma unroll
      for (int jt = 0; jt < 4; ++jt)
        acc[jt] = __builtin_amdgcn_mfma_f32_16x16x32_bf16(a, Wf[kb][jt], acc[jt], 0, 0, 0);
    }

    // epilogue: lane writes col = 64w+lane (jt = g), rows r=0..3
#pragma unroll
    for (int r = 0; r < 4; ++r) {
      float v = acc[0][r];
      v = (g == 1) ? acc[1][r] : v;
      v = (g == 2) ? acc[2][r] : v;
      v = (g == 3) ? acc[3][r] : v;
      hid[((size_t)(b0 + r) * T_ + t) * H_ + 64 * w + lane] = v;          // hidden = h_next (f32)
      hbuf[nxt][r][64 * w + lane] = f2bf(fast_tanh(v));                    // operand for next step
    }

    __syncthreads();
  }
}

// ---------------------------------------------------------------------------
// out = hidden @ W_out^T : memory-bound [BT,512]x[512,64] MFMA GEMM.
// Each wave preloads all W_out fragments (256 VGPR) and grid-strides M-tiles.
// ---------------------------------------------------------------------------
#define OP_BLOCKS 1024
#define OP_WAVES  4
__global__ __launch_bounds__(OP_WAVES * 64) void out_proj(
    const float* __restrict__ hid, const float* __restrict__ Wout,
    float* __restrict__ out)
{
  const int tid  = threadIdx.x;
  const int lane = tid & 63;
  const int w    = tid >> 6;
  const int g    = lane >> 4;
  const int m    = lane & 15;

  bf16x8 Bf[16][4];
#pragma unroll
  for (int kb = 0; kb < 16; ++kb) {
#pragma unroll
    for (int jt = 0; jt < 4; ++jt) {
      const int o = 16 * jt + m;
      const float4* p = reinterpret_cast<const float4*>(Wout + o * H_ + 32 * kb + 8 * g);
      Bf[kb][jt] = pack8(p[0], p[1]);
    }
  }

  const f32x4 zero = {0.f, 0.f, 0.f, 0.f};
  const int wave_id = blockIdx.x * OP_WAVES + w;           // 0..4095
  const int NTILES  = (B_ * T_) / 16;                      // 16384

  for (int tile = wave_id; tile < NTILES; tile += OP_BLOCKS * OP_WAVES) {
    const size_t row0 = (size_t)tile * 16;
    f32x4 acc[4];
#pragma unroll
    for (int jt = 0; jt < 4; ++jt) acc[jt] = zero;

#pragma unroll
    for (int kb = 0; kb < 16; ++kb) {
      const float4* p = reinterpret_cast<const float4*>(hid + (row0 + m) * H_ + 32 * kb + 8 * g);
      const bf16x8 a = pack8(p[0], p[1]);
#pragma unroll
      for (int jt = 0; jt < 4; ++jt)
        acc[jt] = __builtin_amdgcn_mfma_f32_16x16x32_bf16(a, Bf[kb][jt], acc[jt], 0, 0, 0);
    }

#pragma unroll
    for (int jt = 0; jt < 4; ++jt) {
#pragma unroll
      for (int r = 0; r < 4; ++r)
        out[(row0 + 4 * g + r) * NOUT_ + 16 * jt + m] = acc[jt][r];
    }
  }
}

extern "C" void kernel_launch(void* const* d_in, const int* in_sizes, int n_in,
                              void* d_out, int out_size, void* d_ws, size_t ws_size,
                              hipStream_t stream) {
  const float* X    = (const float*)d_in[0];
  const float* h0   = (const float*)d_in[1];
  const float* W    = (const float*)d_in[2];
  const float* Win  = (const float*)d_in[3];
  const float* Wout = (const float*)d_in[4];

  float* out = (float*)d_out;                                   // [B,T,64]
  float* hid = (float*)d_out + (size_t)B_ * T_ * NOUT_;         // [B,T,512]

  rnn_scan<<<dim3(B_ / BBLK), dim3(NW * 64), 0, stream>>>(X, h0, W, Win, hid);
  out_proj<<<dim3(OP_BLOCKS), dim3(OP_WAVES * 64), 0, stream>>>(hid, Wout, out);
}

// Round 2
// 2583.477 us; speedup vs baseline: 2.4102x; 2.4102x over previous
//
#include <hip/hip_runtime.h>
#include <stdint.h>

#define B_    256
#define T_    1024
#define H_    512
#define NIN_  64
#define NOUT_ 64

#define NW     8       // waves per workgroup (recurrent kernel)
#define BBLK   4       // batch rows per workgroup
#define KB_TOT 18      // K = 576 = 512 (W) + 64 (Win), in 32-wide blocks
#define KB_REG 14      // kb 0..13 resident in registers (224 VGPR/wave)
#define KB_LDS 4       // kb 14..17 resident in LDS (14,15 = W tail; 16,17 = Win)
#define HROW   592     // hbuf row stride in shorts (576 + 16 pad -> 2-way max)

typedef __attribute__((ext_vector_type(8))) short bf16x8;
typedef __attribute__((ext_vector_type(4))) float f32x4;

__device__ __forceinline__ short f2bf(float f) {
  uint32_t u = __float_as_uint(f);
  uint32_t r = (u + 0x7FFFu + ((u >> 16) & 1u)) >> 16;
  return (short)(r & 0xFFFFu);
}

__device__ __forceinline__ bf16x8 pack8(float4 lo, float4 hi) {
  bf16x8 s;
  s[0] = f2bf(lo.x); s[1] = f2bf(lo.y); s[2] = f2bf(lo.z); s[3] = f2bf(lo.w);
  s[4] = f2bf(hi.x); s[5] = f2bf(hi.y); s[6] = f2bf(hi.z); s[7] = f2bf(hi.w);
  return s;
}

__device__ __forceinline__ float fast_tanh(float x) {
  float e = __expf(2.0f * x);
  return 1.0f - __fdividef(2.0f, e + 1.0f);
}

// ---------------------------------------------------------------------------
// Persistent RNN scan. 64 WGs x 8 waves. Wave w owns output cols [64w,64w+64).
// W-concat = [W ; Win] over K=576. kb 0..13 of B-fragments live in VGPRs
// (224/wave, 448KB/CU); kb 14..17 live in LDS (128KB/CU), re-read each step.
// A = [tanh(h_t), X_t] lives in a double-buffered LDS row set (broadcast reads).
// One raw s_barrier per step; global hid stores are never vmcnt-drained.
// ---------------------------------------------------------------------------
__global__ __launch_bounds__(NW * 64, 2) void rnn_scan(
    const float* __restrict__ X, const float* __restrict__ h0,
    const float* __restrict__ W, const float* __restrict__ Win,
    float* __restrict__ hid)
{
  __shared__ __align__(16) short wlds[KB_LDS][H_][32];   // 128 KB
  __shared__ __align__(16) short hbuf[2][BBLK][HROW];    // 9.25 KB

  const int tid  = threadIdx.x;
  const int lane = tid & 63;
  const int w    = tid >> 6;    // wave 0..7
  const int g    = lane >> 4;   // k-group 0..3
  const int m    = lane & 15;   // M/N lane index
  const int b0   = blockIdx.x * BBLK;

  // --- register-resident B-fragments: kb 0..13 (columns j = 64w+16jt+m)
  bf16x8 Wf[KB_REG][4];
#pragma unroll
  for (int kb = 0; kb < KB_REG; ++kb) {
#pragma unroll
    for (int jt = 0; jt < 4; ++jt) {
      const int j = 64 * w + 16 * jt + m;
      const float4* p = reinterpret_cast<const float4*>(W + (size_t)j * H_ + 32 * kb + 8 * g);
      Wf[kb][jt] = pack8(p[0], p[1]);
    }
  }

  // --- stage LDS-resident B-fragments: kb 14,15 from W; kb 16,17 from Win
  // 8192 chunks of 8 bf16
#pragma unroll
  for (int i = 0; i < 16; ++i) {
    const int c   = tid + 512 * i;
    const int kbp = c >> 11;          // 0..3
    const int col = (c >> 2) & 511;
    const int q   = (c & 3) * 8;
    const float* src = (kbp < 2) ? (W   + (size_t)col * H_   + 32 * (KB_REG + kbp) + q)
                                 : (Win + (size_t)col * NIN_ + 32 * (kbp - 2)      + q);
    const float4* p = reinterpret_cast<const float4*>(src);
    *reinterpret_cast<bf16x8*>(&wlds[kbp][col][q]) = pack8(p[0], p[1]);
  }

  // --- stage A for t=0: tanh(h0) and X_0
  for (int e = tid; e < BBLK * H_; e += NW * 64) {
    const int r = e >> 9, k = e & (H_ - 1);
    hbuf[0][r][k] = f2bf(fast_tanh(h0[(size_t)(b0 + r) * H_ + k]));
  }
  if (tid < BBLK * NIN_) {
    const int r = tid >> 6, kk = tid & 63;
    hbuf[0][r][H_ + kk] = f2bf(X[((size_t)(b0 + r) * T_ + 0) * NIN_ + kk]);
  }
  __syncthreads();

  for (int t = 0; t < T_; ++t) {
    const int cur = t & 1, nxt = cur ^ 1;
    const short* hrow = &hbuf[cur][m & 3][0];

    // X prefetch for t+1 (1 f32/thread on waves 0..3; issued early)
    float xpf = 0.f;
    {
      const int tn = (t + 1 < T_) ? (t + 1) : t;
      if (tid < BBLK * NIN_)
        xpf = X[((size_t)(b0 + (tid >> 6)) * T_ + tn) * NIN_ + (tid & 63)];
    }

    f32x4 acc[4];
    // LDS-resident kbs first (first one initializes acc)
    {
      const bf16x8 a = *reinterpret_cast<const bf16x8*>(hrow + 32 * KB_REG + 8 * g);
#pragma unroll
      for (int jt = 0; jt < 4; ++jt) {
        const bf16x8 b = *reinterpret_cast<const bf16x8*>(&wlds[0][64 * w + 16 * jt + m][8 * g]);
        const f32x4 zero = {0.f, 0.f, 0.f, 0.f};
        acc[jt] = __builtin_amdgcn_mfma_f32_16x16x32_bf16(a, b, zero, 0, 0, 0);
      }
    }
#pragma unroll
    for (int kb = KB_REG + 1; kb < KB_TOT; ++kb) {
      const bf16x8 a = *reinterpret_cast<const bf16x8*>(hrow + 32 * kb + 8 * g);
#pragma unroll
      for (int jt = 0; jt < 4; ++jt) {
        const bf16x8 b = *reinterpret_cast<const bf16x8*>(&wlds[kb - KB_REG][64 * w + 16 * jt + m][8 * g]);
        acc[jt] = __builtin_amdgcn_mfma_f32_16x16x32_bf16(a, b, acc[jt], 0, 0, 0);
      }
    }
    // register-resident kbs
#pragma unroll
    for (int kb = 0; kb < KB_REG; ++kb) {
      const bf16x8 a = *reinterpret_cast<const bf16x8*>(hrow + 32 * kb + 8 * g);
#pragma unroll
      for (int jt = 0; jt < 4; ++jt)
        acc[jt] = __builtin_amdgcn_mfma_f32_16x16x32_bf16(a, Wf[kb][jt], acc[jt], 0, 0, 0);
    }

    // epilogue: lane writes col = 64w+lane (jt == g); D row 4g+r is batch row r
#pragma unroll
    for (int r = 0; r < 4; ++r) {
      float v = acc[0][r];
      v = (g == 1) ? acc[1][r] : v;
      v = (g == 2) ? acc[2][r] : v;
      v = (g == 3) ? acc[3][r] : v;
      hid[((size_t)(b0 + r) * T_ + t) * H_ + 64 * w + lane] = v;
      hbuf[nxt][r][64 * w + lane] = f2bf(fast_tanh(v));
    }
    if (tid < BBLK * NIN_)
      hbuf[nxt][tid >> 6][H_ + (tid & 63)] = f2bf(xpf);

    // LDS-only drain + barrier: do NOT drain vmcnt (hid stores stream out)
    asm volatile("s_waitcnt lgkmcnt(0)" ::: "memory");
    __builtin_amdgcn_s_barrier();
  }
}

// ---------------------------------------------------------------------------
// out = hidden @ W_out^T : memory-bound [BT,512]x[512,64] MFMA GEMM.
// Wout staged once per block into LDS as bf16 fragments (64 KB); waves
// grid-stride 16-row M-tiles. VGPR-light -> high occupancy.
// ---------------------------------------------------------------------------
#define OP_BLOCKS 1024
#define OP_WAVES  8
__global__ __launch_bounds__(OP_WAVES * 64, 2) void out_proj(
    const float* __restrict__ hid, const float* __restrict__ Wout,
    float* __restrict__ out)
{
  __shared__ __align__(16) short ws[16][NOUT_][32];   // 64 KB

  const int tid  = threadIdx.x;
  const int lane = tid & 63;
  const int w    = tid >> 6;
  const int g    = lane >> 4;
  const int m    = lane & 15;

  // stage Wout -> LDS bf16: 4096 chunks of 8
#pragma unroll
  for (int i = 0; i < 8; ++i) {
    const int c   = tid + OP_WAVES * 64 * i;
    const int kb  = c >> 8;
    const int col = (c >> 2) & 63;
    const int q   = (c & 3) * 8;
    const float4* p = reinterpret_cast<const float4*>(Wout + (size_t)col * H_ + 32 * kb + q);
    *reinterpret_cast<bf16x8*>(&ws[kb][col][q]) = pack8(p[0], p[1]);
  }
  __syncthreads();

  const int wave_id = blockIdx.x * OP_WAVES + w;
  const int NWAVES  = OP_BLOCKS * OP_WAVES;
  const int NTILES  = (B_ * T_) / 16;    // 16384

  for (int tile = wave_id; tile < NTILES; tile += NWAVES) {
    const size_t row0 = (size_t)tile * 16;
    f32x4 acc[4];
    {
      const float4* p = reinterpret_cast<const float4*>(hid + (row0 + m) * H_ + 8 * g);
      const bf16x8 a = pack8(p[0], p[1]);
#pragma unroll
      for (int jt = 0; jt < 4; ++jt) {
        const bf16x8 b = *reinterpret_cast<const bf16x8*>(&ws[0][16 * jt + m][8 * g]);
        const f32x4 zero = {0.f, 0.f, 0.f, 0.f};
        acc[jt] = __builtin_amdgcn_mfma_f32_16x16x32_bf16(a, b, zero, 0, 0, 0);
      }
    }
#pragma unroll
    for (int kb = 1; kb < 16; ++kb) {
      const float4* p = reinterpret_cast<const float4*>(hid + (row0 + m) * H_ + 32 * kb + 8 * g);
      const bf16x8 a = pack8(p[0], p[1]);
#pragma unroll
      for (int jt = 0; jt < 4; ++jt) {
        const bf16x8 b = *reinterpret_cast<const bf16x8*>(&ws[kb][16 * jt + m][8 * g]);
        acc[jt] = __builtin_amdgcn_mfma_f32_16x16x32_bf16(a, b, acc[jt], 0, 0, 0);
      }
    }
#pragma unroll
    for (int jt = 0; jt < 4; ++jt) {
#pragma unroll
      for (int r = 0; r < 4; ++r)
        out[(row0 + 4 * g + r) * NOUT_ + 16 * jt + m] = acc[jt][r];
    }
  }
}

extern "C" void kernel_launch(void* const* d_in, const int* in_sizes, int n_in,
                              void* d_out, int out_size, void* d_ws, size_t ws_size,
                              hipStream_t stream) {
  const float* X    = (const float*)d_in[0];
  const float* h0   = (const float*)d_in[1];
  const float* W    = (const float*)d_in[2];
  const float* Win  = (const float*)d_in[3];
  const float* Wout = (const float*)d_in[4];

  float* out = (float*)d_out;                                   // [B,T,64]
  float* hid = (float*)d_out + (size_t)B_ * T_ * NOUT_;         // [B,T,512]

  rnn_scan<<<dim3(B_ / BBLK), dim3(NW * 64), 0, stream>>>(X, h0, W, Win, hid);
  out_proj<<<dim3(OP_BLOCKS), dim3(OP_WAVES * 64), 0, stream>>>(hid, Wout, out);
}